// Round 2
// baseline (394.900 us; speedup 1.0000x reference)
//
#include <hip/hip_runtime.h>
#include <hip/hip_bf16.h>
#include <math.h>

// Problem constants
#define N_TOK  16384
#define DMODEL 1024
#define GRAPHS 32
#define SEGLEN 512
#define HEADS  16
#define DH     64
#define D3     3072
#define QK_LD  2048   // qkA row stride (Q|K halves)

typedef __bf16 bf16;
typedef __attribute__((ext_vector_type(4))) __bf16 bf16x4;
typedef __attribute__((ext_vector_type(8))) __bf16 bf16x8;
typedef __attribute__((ext_vector_type(4))) float f32x4;

// async global->LDS, 16B per lane; LDS dest must be wave-uniform base + lane*16
__device__ __forceinline__ void async_copy16(const void* g, void* l) {
    __builtin_amdgcn_global_load_lds(
        (const __attribute__((address_space(1))) void*)g,
        (__attribute__((address_space(3))) void*)l, 16, 0, 0);
}

// ---------------- fp32 -> bf16 convert (vectorized) ----------------
__global__ __launch_bounds__(256) void cvt_f32_bf16(const float* __restrict__ in,
                                                    bf16* __restrict__ out, int n4) {
    int i = blockIdx.x * blockDim.x + threadIdx.x;
    if (i < n4) {
        float4 v = ((const float4*)in)[i];
        bf16x4 o;
        o[0] = (bf16)v.x; o[1] = (bf16)v.y; o[2] = (bf16)v.z; o[3] = (bf16)v.w;
        ((bf16x4*)out)[i] = o;
    }
}

// ---------------- GEMM: C[M][N] = A[M][K] * B[N][K]^T (+bias, epilogue variants) ----
// m97 structure: 128x128 tile, BK=64, linear LDS [128][64] bf16, global_load_lds x16B,
// 4 waves (2x2), 16x16x32 bf16 MFMA.
// EPI=0: bf16 store. With VSPLIT: cols<1024 scaled by 0.125 (Q pre-scale for softmax),
//        cols in [2048,3072) routed to vT[g*16+h][d][s] transposed layout.
// EPI=1: f32 store + resid add.
template<int EPI, int VSPLIT>
__global__ __launch_bounds__(256) void gemm_bt(
    const bf16* __restrict__ A, const bf16* __restrict__ B,
    const float* __restrict__ bias, const float* __restrict__ resid,
    void* __restrict__ C, bf16* __restrict__ vT,
    int M, int N, int K, int ldc)
{
    __shared__ alignas(16) char smem[32768];   // A tile 16KB | B tile 16KB
    const int bm0 = blockIdx.x * 128;
    const int bn0 = blockIdx.y * 128;
    const int tid = threadIdx.x;
    const int lane = tid & 63, w = tid >> 6;
    const int wr = w >> 1, wc = w & 1;
    const int l15 = lane & 15, l4 = lane >> 4;

    f32x4 acc[4][4] = {};

    for (int k0 = 0; k0 < K; k0 += 64) {
        #pragma unroll
        for (int q = 0; q < 4; q++) {
            int c = q * 256 + tid;             // 0..1023 chunk id
            int row = c >> 3, kb = c & 7;
            async_copy16(A + (size_t)(bm0 + row) * K + k0 + kb * 8, smem + c * 16);
            async_copy16(B + (size_t)(bn0 + row) * K + k0 + kb * 8, smem + 16384 + c * 16);
        }
        __syncthreads();                        // compiler drains vmcnt before barrier
        #pragma unroll
        for (int kp = 0; kp < 2; kp++) {
            bf16x8 af[4], bfr[4];
            #pragma unroll
            for (int m = 0; m < 4; m++)
                af[m] = *(const bf16x8*)(smem + (wr * 64 + m * 16 + l15) * 128 + (kp * 4 + l4) * 16);
            #pragma unroll
            for (int n = 0; n < 4; n++)
                bfr[n] = *(const bf16x8*)(smem + 16384 + (wc * 64 + n * 16 + l15) * 128 + (kp * 4 + l4) * 16);
            #pragma unroll
            for (int m = 0; m < 4; m++)
                #pragma unroll
                for (int n = 0; n < 4; n++)
                    acc[m][n] = __builtin_amdgcn_mfma_f32_16x16x32_bf16(af[m], bfr[n], acc[m][n], 0, 0, 0);
        }
        __syncthreads();
    }

    // epilogue: C/D layout col=lane&15, row=(lane>>4)*4+i
    #pragma unroll
    for (int m = 0; m < 4; m++) {
        #pragma unroll
        for (int n = 0; n < 4; n++) {
            int col = bn0 + wc * 64 + n * 16 + l15;
            float bv = bias[col];
            #pragma unroll
            for (int i = 0; i < 4; i++) {
                int row = bm0 + wr * 64 + m * 16 + l4 * 4 + i;
                float v = acc[m][n][i] + bv;
                if (EPI == 1) {
                    v += resid[(size_t)row * N + col];
                    ((float*)C)[(size_t)row * N + col] = v;
                } else if (VSPLIT && bn0 >= 2048) {
                    // V -> transposed layout vT[(g*16+h)*64 + d][512 s]
                    int cc = col - 2048;
                    size_t vidx = ((size_t)((row >> 9) * HEADS + (cc >> 6)) * DH + (cc & 63)) * SEGLEN
                                  + (row & (SEGLEN - 1));
                    vT[vidx] = (bf16)v;
                } else {
                    if (VSPLIT && bn0 < 1024) v *= 0.125f;   // fold softmax scale into Q
                    ((bf16*)C)[(size_t)row * ldc + col] = (bf16)v;
                }
            }
        }
    }
}

// ---------------- block-diagonal flash attention ----------------
// grid: (qt=8, h=16, g=32); 256 threads (4 waves), each wave owns 16 q-rows.
// K staged from qkA, V^T staged from vT (both 16B-vectorized, XOR-swizzled),
// next tile reg-prefetched. Q region of LDS reused for P after hoist.
__global__ __launch_bounds__(256) void attn_kernel(
    const bf16* __restrict__ qkA, const bf16* __restrict__ vT, bf16* __restrict__ ctx)
{
    const int qt = blockIdx.x, h = blockIdx.y, g = blockIdx.z;
    __shared__ bf16x8 smQP[64 * 8];   // Q tile, then P tile
    __shared__ bf16x8 smK[64 * 8];
    __shared__ bf16x8 smV[64 * 8];    // V^T tile: [d][kv]
    const int tid = threadIdx.x, lane = tid & 63, w = tid >> 6;
    const int l15 = lane & 15, l4 = lane >> 4;
    const int grow0 = g * SEGLEN;
    const size_t vbase = (size_t)(g * HEADS + h) * DH * SEGLEN;

    // stage Q tile (pre-scaled by 0.125 in GEMM1 epilogue)
    #pragma unroll
    for (int q = 0; q < 2; q++) {
        int c = tid + 256 * q, r = c >> 3, cb = c & 7;
        uint4 v = *(const uint4*)(qkA + (size_t)(grow0 + qt * 64 + r) * QK_LD + h * 64 + cb * 8);
        smQP[r * 8 + (cb ^ (r & 7))] = __builtin_bit_cast(bf16x8, v);
    }
    __syncthreads();

    // hoist Q fragments (wave's 16 rows)
    bf16x8 qf[2];
    #pragma unroll
    for (int kp = 0; kp < 2; kp++) {
        int row = w * 16 + l15;
        qf[kp] = smQP[row * 8 + ((kp * 4 + l4) ^ (row & 7))];
    }

    f32x4 acc[4] = {};
    float mrow[4], lrow[4];
    #pragma unroll
    for (int i = 0; i < 4; i++) { mrow[i] = -INFINITY; lrow[i] = 0.f; }

    uint4 kr[2][2], vr[2][2];
    auto LOADT = [&](int t, int dst) {
        #pragma unroll
        for (int q = 0; q < 2; q++) {
            int c = tid + 256 * q, r = c >> 3, cb = c & 7;
            kr[dst][q] = *(const uint4*)(qkA + (size_t)(grow0 + t * 64 + r) * QK_LD + 1024 + h * 64 + cb * 8);
            vr[dst][q] = *(const uint4*)(vT + vbase + (size_t)r * SEGLEN + t * 64 + cb * 8);
        }
    };
    LOADT(0, 0);

    #pragma unroll
    for (int t = 0; t < 8; t++) {
        const int cur = t & 1, nxt = cur ^ 1;
        // write prefetched tile to LDS
        #pragma unroll
        for (int q = 0; q < 2; q++) {
            int c = tid + 256 * q, r = c >> 3, cb = c & 7;
            smK[r * 8 + (cb ^ (r & 7))] = __builtin_bit_cast(bf16x8, kr[cur][q]);
            smV[r * 8 + (cb ^ (r & 7))] = __builtin_bit_cast(bf16x8, vr[cur][q]);
        }
        if (t < 7) LOADT(t + 1, nxt);   // issue next-tile loads; latency hides under compute
        __syncthreads();

        // S = Q K^T (16 q-rows x 64 kv), already softmax-scaled
        f32x4 s[4] = {};
        #pragma unroll
        for (int kp = 0; kp < 2; kp++) {
            #pragma unroll
            for (int n = 0; n < 4; n++) {
                int row = n * 16 + l15;
                bf16x8 kf = smK[row * 8 + ((kp * 4 + l4) ^ (row & 7))];
                s[n] = __builtin_amdgcn_mfma_f32_16x16x32_bf16(qf[kp], kf, s[n], 0, 0, 0);
            }
        }
        // row max (frags then 16-lane reduce)
        float mx[4];
        #pragma unroll
        for (int i = 0; i < 4; i++) {
            float m0 = fmaxf(fmaxf(s[0][i], s[1][i]), fmaxf(s[2][i], s[3][i]));
            #pragma unroll
            for (int d = 1; d < 16; d <<= 1) m0 = fmaxf(m0, __shfl_xor(m0, d));
            mx[i] = m0;
        }
        // defer-max: only rescale when the running max grew by > 8
        int need = 0;
        #pragma unroll
        for (int i = 0; i < 4; i++) need |= (mx[i] > mrow[i] + 8.0f) ? 1 : 0;
        if (__any(need)) {
            #pragma unroll
            for (int i = 0; i < 4; i++) {
                float mn = fmaxf(mrow[i], mx[i]);
                float alpha = __expf(mrow[i] - mn);   // first tile: exp(-inf)=0
                mrow[i] = mn;
                lrow[i] *= alpha;
                #pragma unroll
                for (int n = 0; n < 4; n++) acc[n][i] *= alpha;
            }
        }
        // P = exp(s - m) -> LDS (bf16, swizzled), rowsum
        float rsum[4] = {0.f, 0.f, 0.f, 0.f};
        #pragma unroll
        for (int n = 0; n < 4; n++) {
            #pragma unroll
            for (int i = 0; i < 4; i++) {
                float p = __expf(s[n][i] - mrow[i]);  // bounded by e^8
                rsum[i] += p;
                int prow = w * 16 + l4 * 4 + i;
                int pcol = n * 16 + l15;
                ((bf16*)smQP)[prow * 64 + (pcol ^ ((prow & 7) << 3))] = (bf16)p;
            }
        }
        #pragma unroll
        for (int i = 0; i < 4; i++) {
            #pragma unroll
            for (int d = 1; d < 16; d <<= 1) rsum[i] += __shfl_xor(rsum[i], d);
            lrow[i] += rsum[i];
        }
        // PV: acc += P * V^T-rows (P rows = wave's own rows; same-wave ds order is safe)
        #pragma unroll
        for (int kp = 0; kp < 2; kp++) {
            int prow = w * 16 + l15;
            bf16x8 pf = smQP[prow * 8 + ((kp * 4 + l4) ^ (prow & 7))];
            #pragma unroll
            for (int n = 0; n < 4; n++) {
                int vrow = n * 16 + l15;
                bf16x8 vf = smV[vrow * 8 + ((kp * 4 + l4) ^ (vrow & 7))];
                acc[n] = __builtin_amdgcn_mfma_f32_16x16x32_bf16(pf, vf, acc[n], 0, 0, 0);
            }
        }
        __syncthreads();
    }

    // epilogue: ctx[row][h*64 + col] = acc / l
    #pragma unroll
    for (int i = 0; i < 4; i++) {
        float inv = 1.f / lrow[i];
        int row = grow0 + qt * 64 + w * 16 + l4 * 4 + i;
        #pragma unroll
        for (int n = 0; n < 4; n++) {
            int col = h * 64 + n * 16 + l15;
            ctx[(size_t)row * DMODEL + col] = (bf16)(acc[n][i] * inv);
        }
    }
}

// ---------------- residual+GEMM output -> LayerNorm ----------------
__global__ __launch_bounds__(256) void ln_kernel(
    const float* __restrict__ h, const float* __restrict__ gamma,
    const float* __restrict__ beta, float* __restrict__ out)
{
    const int row = blockIdx.x;
    float4 v = ((const float4*)(h + (size_t)row * DMODEL))[threadIdx.x];
    float s  = v.x + v.y + v.z + v.w;
    float ss = v.x * v.x + v.y * v.y + v.z * v.z + v.w * v.w;
    #pragma unroll
    for (int d = 1; d < 64; d <<= 1) { s += __shfl_xor(s, d); ss += __shfl_xor(ss, d); }
    __shared__ float red[8];
    int wv = threadIdx.x >> 6, lane = threadIdx.x & 63;
    if (lane == 0) { red[wv] = s; red[4 + wv] = ss; }
    __syncthreads();
    s  = red[0] + red[1] + red[2] + red[3];
    ss = red[4] + red[5] + red[6] + red[7];
    float mu  = s * (1.f / 1024.f);
    float var = ss * (1.f / 1024.f) - mu * mu;
    float rs  = rsqrtf(var + 1e-5f);
    float4 gv = ((const float4*)gamma)[threadIdx.x];
    float4 bv = ((const float4*)beta)[threadIdx.x];
    float4 o;
    o.x = (v.x - mu) * rs * gv.x + bv.x;
    o.y = (v.y - mu) * rs * gv.y + bv.y;
    o.z = (v.z - mu) * rs * gv.z + bv.z;
    o.w = (v.w - mu) * rs * gv.w + bv.w;
    ((float4*)(out + (size_t)row * DMODEL))[threadIdx.x] = o;
}

// ---------------- launch ----------------
extern "C" void kernel_launch(void* const* d_in, const int* in_sizes, int n_in,
                              void* d_out, int out_size, void* d_ws, size_t ws_size,
                              hipStream_t stream) {
    const float* x     = (const float*)d_in[0];
    // d_in[1] = batch (int64) — fixed 512-row segments, unused
    const float* w_in  = (const float*)d_in[2];
    const float* b_in  = (const float*)d_in[3];
    const float* w_out = (const float*)d_in[4];
    const float* b_out = (const float*)d_in[5];
    const float* gamma = (const float*)d_in[6];
    const float* beta  = (const float*)d_in[7];
    float* out = (float*)d_out;

    // workspace layout (~136 MB):
    //   [0, 32M)     xb  (bf16 x)          -> reused as ctx (bf16) after GEMM1
    //   [32M, 38M)   wb  (bf16 w_in)
    //   [38M, 40M)   wob (bf16 w_out)
    //   [40M, 104M)  qkA (bf16 [N][2048], Q|K; Q pre-scaled) -> reused as h (f32) after attn
    //   [104M, 136M) vT  (bf16 [32*16*64][512], V transposed)
    char* ws = (char*)d_ws;
    bf16*  xb   = (bf16*)ws;
    bf16*  wb   = (bf16*)(ws + 33554432);
    bf16*  wob  = (bf16*)(ws + 39845888);
    bf16*  qkA  = (bf16*)(ws + 41943040);
    bf16*  vT   = (bf16*)(ws + 109051904);
    bf16*  ctxb = xb;              // alias: xb dead after GEMM1
    float* hbuf = (float*)qkA;     // alias: qkA dead after attention

    // 1) converts
    cvt_f32_bf16<<<16384, 256, 0, stream>>>(x,     xb,  N_TOK * DMODEL / 4);
    cvt_f32_bf16<<<3072,  256, 0, stream>>>(w_in,  wb,  D3 * DMODEL / 4);
    cvt_f32_bf16<<<1024,  256, 0, stream>>>(w_out, wob, DMODEL * DMODEL / 4);

    // 2) qkv = x @ w_in.T + b_in  -> qkA (Q scaled) + vT (V transposed)
    gemm_bt<0, 1><<<dim3(128, 24), 256, 0, stream>>>(xb, wb, b_in, nullptr, qkA, vT,
                                                     N_TOK, D3, DMODEL, QK_LD);
    // 3) block-diagonal attention -> ctx (bf16)
    attn_kernel<<<dim3(8, 16, 32), 256, 0, stream>>>(qkA, vT, ctxb);

    // 4) h = ctx @ w_out.T + b_out + x  (f32)
    gemm_bt<1, 0><<<dim3(128, 8), 256, 0, stream>>>(ctxb, wob, b_out, x, hbuf, nullptr,
                                                    N_TOK, DMODEL, DMODEL, DMODEL);
    // 5) LayerNorm
    ln_kernel<<<N_TOK, 256, 0, stream>>>(hbuf, gamma, beta, out);
}

// Round 3
// 355.620 us; speedup vs baseline: 1.1105x; 1.1105x over previous
//
#include <hip/hip_runtime.h>
#include <hip/hip_bf16.h>
#include <math.h>

// Problem constants
#define N_TOK  16384
#define DMODEL 1024
#define GRAPHS 32
#define SEGLEN 512
#define HEADS  16
#define DH     64
#define D3     3072
#define QK_LD  2048   // qkA row stride (Q|K halves)
#define KDIM   1024   // GEMM K (both GEMMs)
#define NT_K   16     // K / 64

typedef __bf16 bf16;
typedef __attribute__((ext_vector_type(4))) __bf16 bf16x4;
typedef __attribute__((ext_vector_type(8))) __bf16 bf16x8;
typedef __attribute__((ext_vector_type(4))) float f32x4;

#define BARRIER()    asm volatile("s_barrier" ::: "memory")
#define WAIT_LGKM0() do { asm volatile("s_waitcnt lgkmcnt(0)" ::: "memory"); \
                          __builtin_amdgcn_sched_barrier(0); } while (0)
#define WAIT_VM4()   do { asm volatile("s_waitcnt vmcnt(4)" ::: "memory"); \
                          __builtin_amdgcn_sched_barrier(0); } while (0)
#define WAIT_VM0()   do { asm volatile("s_waitcnt vmcnt(0)" ::: "memory"); \
                          __builtin_amdgcn_sched_barrier(0); } while (0)

// async global->LDS, 16B per lane; LDS dest must be wave-uniform base + lane*16
__device__ __forceinline__ void async_copy16(const void* g, void* l) {
    __builtin_amdgcn_global_load_lds(
        (const __attribute__((address_space(1))) void*)g,
        (__attribute__((address_space(3))) void*)l, 16, 0, 0);
}

// ---------------- fp32 -> bf16 convert (vectorized) ----------------
__global__ __launch_bounds__(256) void cvt_f32_bf16(const float* __restrict__ in,
                                                    bf16* __restrict__ out, int n4) {
    int i = blockIdx.x * blockDim.x + threadIdx.x;
    if (i < n4) {
        float4 v = ((const float4*)in)[i];
        bf16x4 o;
        o[0] = (bf16)v.x; o[1] = (bf16)v.y; o[2] = (bf16)v.z; o[3] = (bf16)v.w;
        ((bf16x4*)out)[i] = o;
    }
}

// ============ 256x256 8-phase GEMM: C[M][N] = A[M][K] * B[N][K]^T (+bias) ============
// K fixed = 1024 (NT_K=16 K-tiles of 64). 512 threads = 8 waves (2 Mwave x 4 Nwave),
// per-wave output 128x64 (8 m-frags x 4 n-frags), 16x16x32 bf16 MFMA.
// LDS 128KiB: 2 buffers x (A 32KB | B 32KB). st_16x32 swizzle: tile stored as
// [16-row][32-col] 1024B subtiles, local byte ^= ((r&15)>>3)<<5. gload_lds writes
// LINEAR; the global source address is inverse-swizzled per lane (rule #21).
// Per K-tile: 4 phases {ds_read frags; stage 1 half-tile; barrier; lgkmcnt(0);
// setprio(1); 16 MFMA; setprio(0); barrier}; counted vmcnt(4) only at phase 4.
// Half-tile stage slots: ph1=(t+1)A-lo, ph2=(t+1)A-hi, ph3=(t+2)B-lo, ph4=(t+2)B-hi.
// Safety: B halves of cur buf are fully read after ph2, A halves after ph3 (verified
// per-wave read sets); vmcnt(4) at ph4 completes everything except the 2 newest
// B-halves -> tile t+1 fully resident before its ph1 reads.
template<int EPI, int VSPLIT>   // EPI 0: bf16 (+VSPLIT routing); EPI 1: f32 + resid
__global__ __launch_bounds__(512, 2) void gemm256(
    const bf16* __restrict__ A, const bf16* __restrict__ B,
    const float* __restrict__ bias, const float* __restrict__ resid,
    void* __restrict__ C, bf16* __restrict__ vT, int N, int nbn, int ldc)
{
    extern __shared__ __align__(16) char smem[];   // 131072 bytes
    const int tid  = threadIdx.x;
    const int lane = tid & 63;
    const int w    = tid >> 6;
    const int wr   = w >> 2, wc = w & 3;
    const int l15  = lane & 15, l4 = lane >> 4;

    // XCD-aware bijective swizzle (gridDim.x % 8 == 0 for both call sites)
    const int nwg = (int)gridDim.x;
    const int bid = (int)blockIdx.x;
    const int sw  = (bid & 7) * (nwg >> 3) + (bid >> 3);
    const int mt  = sw / nbn, nt = sw % nbn;
    const int bm0 = mt * 256, bn0 = nt * 256;

    // staging decode: chunk c -> (row, k) inside a 128x64 half-tile, pre-swizzled
    int rdec[2], kdec[2];
    #pragma unroll
    for (int q = 0; q < 2; q++) {
        int c = q * 512 + tid;
        int P = c * 16;
        int L = P ^ (((P >> 9) & 1) << 5);
        rdec[q] = ((L >> 10) >> 1) * 16 + ((L >> 6) & 15);
        kdec[q] = ((L >> 10) & 1) * 32 + ((L & 63) >> 1);
    }

    auto STAGE_A = [&](int t, int h) {
        const int buf = t & 1, k0 = t * 64;
        #pragma unroll
        for (int q = 0; q < 2; q++) {
            const bf16* src = A + (size_t)(bm0 + h * 128 + rdec[q]) * KDIM + k0 + kdec[q];
            async_copy16(src, smem + buf * 65536 + h * 16384 + (q * 512 + tid) * 16);
        }
    };
    auto STAGE_B = [&](int t, int h) {
        const int buf = t & 1, k0 = t * 64;
        #pragma unroll
        for (int q = 0; q < 2; q++) {
            const bf16* src = B + (size_t)(bn0 + h * 128 + rdec[q]) * KDIM + k0 + kdec[q];
            async_copy16(src, smem + buf * 65536 + 32768 + h * 16384 + (q * 512 + tid) * 16);
        }
    };
    // swizzled ds_read of one 16B frag: tile row r (0..255), 16B k-chunk kc (0..7)
    auto LDA = [&](int buf, int r, int kc) -> bf16x8 {
        int byte = buf * 65536 + ((((r >> 4) << 1) + (kc >> 2)) << 10) + ((r & 15) << 6)
                 + (((kc & 3) << 4) ^ (((r >> 3) & 1) << 5));
        return *(const bf16x8*)(smem + byte);
    };
    auto LDB = [&](int buf, int r, int kc) -> bf16x8 {
        int byte = buf * 65536 + 32768 + ((((r >> 4) << 1) + (kc >> 2)) << 10) + ((r & 15) << 6)
                 + (((kc & 3) << 4) ^ (((r >> 3) & 1) << 5));
        return *(const bf16x8*)(smem + byte);
    };

    f32x4  acc[8][4] = {};
    bf16x8 aq[4][2], bq[4][2];

    // prologue: tile0 fully + tile1 B halves; vmcnt(4) leaves tile1's B in flight
    STAGE_A(0, 0); STAGE_A(0, 1); STAGE_B(0, 0); STAGE_B(0, 1);
    STAGE_B(1, 0); STAGE_B(1, 1);
    WAIT_VM4();
    BARRIER();

    #pragma unroll 1
    for (int t = 0; t < NT_K; ++t) {
        const int buf = t & 1;
        // ---- phase 1: m0-3 x n0-1 ----
        #pragma unroll
        for (int m = 0; m < 4; m++)
            #pragma unroll
            for (int kk = 0; kk < 2; kk++)
                aq[m][kk] = LDA(buf, wr * 128 + m * 16 + l15, kk * 4 + l4);
        #pragma unroll
        for (int n = 0; n < 2; n++)
            #pragma unroll
            for (int kk = 0; kk < 2; kk++)
                bq[n][kk] = LDB(buf, wc * 64 + n * 16 + l15, kk * 4 + l4);
        if (t + 1 < NT_K) STAGE_A(t + 1, 0);
        BARRIER();
        WAIT_LGKM0();
        __builtin_amdgcn_s_setprio(1);
        #pragma unroll
        for (int m = 0; m < 4; m++)
            #pragma unroll
            for (int n = 0; n < 2; n++)
                #pragma unroll
                for (int kk = 0; kk < 2; kk++)
                    acc[m][n] = __builtin_amdgcn_mfma_f32_16x16x32_bf16(aq[m][kk], bq[n][kk], acc[m][n], 0, 0, 0);
        __builtin_amdgcn_s_setprio(0);
        BARRIER();
        // ---- phase 2: m0-3 x n2-3 ----
        #pragma unroll
        for (int n = 2; n < 4; n++)
            #pragma unroll
            for (int kk = 0; kk < 2; kk++)
                bq[n][kk] = LDB(buf, wc * 64 + n * 16 + l15, kk * 4 + l4);
        if (t + 1 < NT_K) STAGE_A(t + 1, 1);
        BARRIER();
        WAIT_LGKM0();
        __builtin_amdgcn_s_setprio(1);
        #pragma unroll
        for (int m = 0; m < 4; m++)
            #pragma unroll
            for (int n = 2; n < 4; n++)
                #pragma unroll
                for (int kk = 0; kk < 2; kk++)
                    acc[m][n] = __builtin_amdgcn_mfma_f32_16x16x32_bf16(aq[m][kk], bq[n][kk], acc[m][n], 0, 0, 0);
        __builtin_amdgcn_s_setprio(0);
        BARRIER();
        // ---- phase 3: m4-7 x n0-1 (reload A subtile into same regs) ----
        #pragma unroll
        for (int m = 0; m < 4; m++)
            #pragma unroll
            for (int kk = 0; kk < 2; kk++)
                aq[m][kk] = LDA(buf, wr * 128 + 64 + m * 16 + l15, kk * 4 + l4);
        if (t + 2 < NT_K) STAGE_B(t + 2, 0);
        BARRIER();
        WAIT_LGKM0();
        __builtin_amdgcn_s_setprio(1);
        #pragma unroll
        for (int m = 0; m < 4; m++)
            #pragma unroll
            for (int n = 0; n < 2; n++)
                #pragma unroll
                for (int kk = 0; kk < 2; kk++)
                    acc[4 + m][n] = __builtin_amdgcn_mfma_f32_16x16x32_bf16(aq[m][kk], bq[n][kk], acc[4 + m][n], 0, 0, 0);
        __builtin_amdgcn_s_setprio(0);
        BARRIER();
        // ---- phase 4: m4-7 x n2-3; counted vmcnt ----
        if (t + 2 < NT_K) STAGE_B(t + 2, 1);
        if (t < NT_K - 2) { WAIT_VM4(); } else { WAIT_VM0(); }
        BARRIER();
        __builtin_amdgcn_s_setprio(1);
        #pragma unroll
        for (int m = 0; m < 4; m++)
            #pragma unroll
            for (int n = 2; n < 4; n++)
                #pragma unroll
                for (int kk = 0; kk < 2; kk++)
                    acc[4 + m][n] = __builtin_amdgcn_mfma_f32_16x16x32_bf16(aq[m][kk], bq[n][kk], acc[4 + m][n], 0, 0, 0);
        __builtin_amdgcn_s_setprio(0);
        BARRIER();
    }

    // epilogue: C/D layout col=lane&15, row=(lane>>4)*4+i
    #pragma unroll
    for (int m = 0; m < 8; m++) {
        #pragma unroll
        for (int n = 0; n < 4; n++) {
            int col = bn0 + wc * 64 + n * 16 + l15;
            float bv = bias[col];
            #pragma unroll
            for (int i = 0; i < 4; i++) {
                int row = bm0 + wr * 128 + m * 16 + l4 * 4 + i;
                float v = acc[m][n][i] + bv;
                if (EPI == 1) {
                    v += resid[(size_t)row * N + col];
                    ((float*)C)[(size_t)row * N + col] = v;
                } else if (VSPLIT && bn0 >= 2048) {
                    // V -> transposed layout vT[(g*16+h)*64 + d][512 s]
                    int cc = col - 2048;
                    size_t vidx = ((size_t)((row >> 9) * HEADS + (cc >> 6)) * DH + (cc & 63)) * SEGLEN
                                  + (row & (SEGLEN - 1));
                    vT[vidx] = (bf16)v;
                } else {
                    if (VSPLIT && bn0 < 1024) v *= 0.125f;   // fold softmax scale into Q
                    ((bf16*)C)[(size_t)row * ldc + col] = (bf16)v;
                }
            }
        }
    }
}

// ---------------- block-diagonal flash attention ----------------
// grid: (qt=8, h=16, g=32); 256 threads (4 waves), each wave owns 16 q-rows.
__global__ __launch_bounds__(256) void attn_kernel(
    const bf16* __restrict__ qkA, const bf16* __restrict__ vT, bf16* __restrict__ ctx)
{
    const int qt = blockIdx.x, h = blockIdx.y, g = blockIdx.z;
    __shared__ bf16x8 smQP[64 * 8];   // Q tile, then P tile
    __shared__ bf16x8 smK[64 * 8];
    __shared__ bf16x8 smV[64 * 8];    // V^T tile: [d][kv]
    const int tid = threadIdx.x, lane = tid & 63, w = tid >> 6;
    const int l15 = lane & 15, l4 = lane >> 4;
    const int grow0 = g * SEGLEN;
    const size_t vbase = (size_t)(g * HEADS + h) * DH * SEGLEN;

    #pragma unroll
    for (int q = 0; q < 2; q++) {
        int c = tid + 256 * q, r = c >> 3, cb = c & 7;
        uint4 v = *(const uint4*)(qkA + (size_t)(grow0 + qt * 64 + r) * QK_LD + h * 64 + cb * 8);
        smQP[r * 8 + (cb ^ (r & 7))] = __builtin_bit_cast(bf16x8, v);
    }
    __syncthreads();

    bf16x8 qf[2];
    #pragma unroll
    for (int kp = 0; kp < 2; kp++) {
        int row = w * 16 + l15;
        qf[kp] = smQP[row * 8 + ((kp * 4 + l4) ^ (row & 7))];
    }

    f32x4 acc[4] = {};
    float mrow[4], lrow[4];
    #pragma unroll
    for (int i = 0; i < 4; i++) { mrow[i] = -INFINITY; lrow[i] = 0.f; }

    uint4 kr[2][2], vr[2][2];
    auto LOADT = [&](int t, int dst) {
        #pragma unroll
        for (int q = 0; q < 2; q++) {
            int c = tid + 256 * q, r = c >> 3, cb = c & 7;
            kr[dst][q] = *(const uint4*)(qkA + (size_t)(grow0 + t * 64 + r) * QK_LD + 1024 + h * 64 + cb * 8);
            vr[dst][q] = *(const uint4*)(vT + vbase + (size_t)r * SEGLEN + t * 64 + cb * 8);
        }
    };
    LOADT(0, 0);

    #pragma unroll
    for (int t = 0; t < 8; t++) {
        const int cur = t & 1, nxt = cur ^ 1;
        #pragma unroll
        for (int q = 0; q < 2; q++) {
            int c = tid + 256 * q, r = c >> 3, cb = c & 7;
            smK[r * 8 + (cb ^ (r & 7))] = __builtin_bit_cast(bf16x8, kr[cur][q]);
            smV[r * 8 + (cb ^ (r & 7))] = __builtin_bit_cast(bf16x8, vr[cur][q]);
        }
        if (t < 7) LOADT(t + 1, nxt);
        __syncthreads();

        f32x4 s[4] = {};
        #pragma unroll
        for (int kp = 0; kp < 2; kp++) {
            #pragma unroll
            for (int n = 0; n < 4; n++) {
                int row = n * 16 + l15;
                bf16x8 kf = smK[row * 8 + ((kp * 4 + l4) ^ (row & 7))];
                s[n] = __builtin_amdgcn_mfma_f32_16x16x32_bf16(qf[kp], kf, s[n], 0, 0, 0);
            }
        }
        float mx[4];
        #pragma unroll
        for (int i = 0; i < 4; i++) {
            float m0 = fmaxf(fmaxf(s[0][i], s[1][i]), fmaxf(s[2][i], s[3][i]));
            #pragma unroll
            for (int d = 1; d < 16; d <<= 1) m0 = fmaxf(m0, __shfl_xor(m0, d));
            mx[i] = m0;
        }
        int need = 0;
        #pragma unroll
        for (int i = 0; i < 4; i++) need |= (mx[i] > mrow[i] + 8.0f) ? 1 : 0;
        if (__any(need)) {
            #pragma unroll
            for (int i = 0; i < 4; i++) {
                float mn = fmaxf(mrow[i], mx[i]);
                float alpha = __expf(mrow[i] - mn);
                mrow[i] = mn;
                lrow[i] *= alpha;
                #pragma unroll
                for (int n = 0; n < 4; n++) acc[n][i] *= alpha;
            }
        }
        float rsum[4] = {0.f, 0.f, 0.f, 0.f};
        #pragma unroll
        for (int n = 0; n < 4; n++) {
            #pragma unroll
            for (int i = 0; i < 4; i++) {
                float p = __expf(s[n][i] - mrow[i]);
                rsum[i] += p;
                int prow = w * 16 + l4 * 4 + i;
                int pcol = n * 16 + l15;
                ((bf16*)smQP)[prow * 64 + (pcol ^ ((prow & 7) << 3))] = (bf16)p;
            }
        }
        #pragma unroll
        for (int i = 0; i < 4; i++) {
            #pragma unroll
            for (int d = 1; d < 16; d <<= 1) rsum[i] += __shfl_xor(rsum[i], d);
            lrow[i] += rsum[i];
        }
        #pragma unroll
        for (int kp = 0; kp < 2; kp++) {
            int prow = w * 16 + l15;
            bf16x8 pf = smQP[prow * 8 + ((kp * 4 + l4) ^ (prow & 7))];
            #pragma unroll
            for (int n = 0; n < 4; n++) {
                int vrow = n * 16 + l15;
                bf16x8 vf = smV[vrow * 8 + ((kp * 4 + l4) ^ (vrow & 7))];
                acc[n] = __builtin_amdgcn_mfma_f32_16x16x32_bf16(pf, vf, acc[n], 0, 0, 0);
            }
        }
        __syncthreads();
    }

    #pragma unroll
    for (int i = 0; i < 4; i++) {
        float inv = 1.f / lrow[i];
        int row = grow0 + qt * 64 + w * 16 + l4 * 4 + i;
        #pragma unroll
        for (int n = 0; n < 4; n++) {
            int col = h * 64 + n * 16 + l15;
            ctx[(size_t)row * DMODEL + col] = (bf16)(acc[n][i] * inv);
        }
    }
}

// ---------------- residual+GEMM output -> LayerNorm ----------------
__global__ __launch_bounds__(256) void ln_kernel(
    const float* __restrict__ h, const float* __restrict__ gamma,
    const float* __restrict__ beta, float* __restrict__ out)
{
    const int row = blockIdx.x;
    float4 v = ((const float4*)(h + (size_t)row * DMODEL))[threadIdx.x];
    float s  = v.x + v.y + v.z + v.w;
    float ss = v.x * v.x + v.y * v.y + v.z * v.z + v.w * v.w;
    #pragma unroll
    for (int d = 1; d < 64; d <<= 1) { s += __shfl_xor(s, d); ss += __shfl_xor(ss, d); }
    __shared__ float red[8];
    int wv = threadIdx.x >> 6, lane = threadIdx.x & 63;
    if (lane == 0) { red[wv] = s; red[4 + wv] = ss; }
    __syncthreads();
    s  = red[0] + red[1] + red[2] + red[3];
    ss = red[4] + red[5] + red[6] + red[7];
    float mu  = s * (1.f / 1024.f);
    float var = ss * (1.f / 1024.f) - mu * mu;
    float rs  = rsqrtf(var + 1e-5f);
    float4 gv = ((const float4*)gamma)[threadIdx.x];
    float4 bv = ((const float4*)beta)[threadIdx.x];
    float4 o;
    o.x = (v.x - mu) * rs * gv.x + bv.x;
    o.y = (v.y - mu) * rs * gv.y + bv.y;
    o.z = (v.z - mu) * rs * gv.z + bv.z;
    o.w = (v.w - mu) * rs * gv.w + bv.w;
    ((float4*)(out + (size_t)row * DMODEL))[threadIdx.x] = o;
}

// ---------------- launch ----------------
extern "C" void kernel_launch(void* const* d_in, const int* in_sizes, int n_in,
                              void* d_out, int out_size, void* d_ws, size_t ws_size,
                              hipStream_t stream) {
    const float* x     = (const float*)d_in[0];
    // d_in[1] = batch (int64) — fixed 512-row segments, unused
    const float* w_in  = (const float*)d_in[2];
    const float* b_in  = (const float*)d_in[3];
    const float* w_out = (const float*)d_in[4];
    const float* b_out = (const float*)d_in[5];
    const float* gamma = (const float*)d_in[6];
    const float* beta  = (const float*)d_in[7];
    float* out = (float*)d_out;

    // workspace layout (~136 MB):
    //   [0, 32M)     xb  (bf16 x)          -> reused as ctx (bf16) after GEMM1
    //   [32M, 38M)   wb  (bf16 w_in)
    //   [38M, 40M)   wob (bf16 w_out)
    //   [40M, 104M)  qkA (bf16 [N][2048], Q|K; Q pre-scaled) -> reused as h (f32) after attn
    //   [104M, 136M) vT  (bf16 [32*16*64][512], V transposed)
    char* ws = (char*)d_ws;
    bf16*  xb   = (bf16*)ws;
    bf16*  wb   = (bf16*)(ws + 33554432);
    bf16*  wob  = (bf16*)(ws + 39845888);
    bf16*  qkA  = (bf16*)(ws + 41943040);
    bf16*  vT   = (bf16*)(ws + 109051904);
    bf16*  ctxb = xb;
    float* hbuf = (float*)qkA;

    // allow 128KiB dynamic LDS (idempotent host-side calls; not stream ops)
    auto* k1 = gemm256<0, 1>;
    auto* k2 = gemm256<1, 0>;
    (void)hipFuncSetAttribute((const void*)k1, hipFuncAttributeMaxDynamicSharedMemorySize, 131072);
    (void)hipFuncSetAttribute((const void*)k2, hipFuncAttributeMaxDynamicSharedMemorySize, 131072);

    // 1) converts
    cvt_f32_bf16<<<16384, 256, 0, stream>>>(x,     xb,  N_TOK * DMODEL / 4);
    cvt_f32_bf16<<<3072,  256, 0, stream>>>(w_in,  wb,  D3 * DMODEL / 4);
    cvt_f32_bf16<<<1024,  256, 0, stream>>>(w_out, wob, DMODEL * DMODEL / 4);

    // 2) qkv = x @ w_in.T + b_in  -> qkA (Q scaled) + vT (V transposed)
    gemm256<0, 1><<<768, 512, 131072, stream>>>(xb, wb, b_in, nullptr, qkA, vT,
                                                D3, 12, QK_LD);
    // 3) block-diagonal attention -> ctx (bf16)
    attn_kernel<<<dim3(8, 16, 32), 256, 0, stream>>>(qkA, vT, ctxb);

    // 4) h = ctx @ w_out.T + b_out + x  (f32)
    gemm256<1, 0><<<256, 512, 131072, stream>>>(ctxb, wob, b_out, x, hbuf, nullptr,
                                                DMODEL, 4, DMODEL);
    // 5) LayerNorm
    ln_kernel<<<N_TOK, 256, 0, stream>>>(hbuf, gamma, beta, out);
}

// Round 4
// 338.382 us; speedup vs baseline: 1.1670x; 1.0509x over previous
//
#include <hip/hip_runtime.h>
#include <hip/hip_bf16.h>
#include <math.h>

// Problem constants
#define N_TOK  16384
#define DMODEL 1024
#define GRAPHS 32
#define SEGLEN 512
#define HEADS  16
#define DH     64
#define D3     3072
#define QK_LD  2048   // qkA row stride (Q|K halves)
#define KDIM   1024   // GEMM K (both GEMMs)
#define NT_K   16     // K / 64

typedef __bf16 bf16;
typedef __attribute__((ext_vector_type(4))) __bf16 bf16x4;
typedef __attribute__((ext_vector_type(8))) __bf16 bf16x8;
typedef __attribute__((ext_vector_type(4))) float f32x4;

// ---------------- fp32 -> bf16 convert (vectorized) ----------------
__global__ __launch_bounds__(256) void cvt_f32_bf16(const float* __restrict__ in,
                                                    bf16* __restrict__ out, int n4) {
    int i = blockIdx.x * blockDim.x + threadIdx.x;
    if (i < n4) {
        float4 v = ((const float4*)in)[i];
        bf16x4 o;
        o[0] = (bf16)v.x; o[1] = (bf16)v.y; o[2] = (bf16)v.z; o[3] = (bf16)v.w;
        ((bf16x4*)out)[i] = o;
    }
}

// ======== 128x128 reg-staged swizzled GEMM, T14 prefetch: C = A * B^T (+bias) ========
// K fixed = 1024. 256 threads = 4 waves (2x2), per-wave 64x64 (4x4 frags of 16x16x32).
// Single 32KB LDS buffer (A 16KB | B 16KB), 16B chunks, XOR swizzle kb^(row&7)
// (2-way bank aliasing on reads = free per m136). T14: issue tile t+1 global loads
// to regs BEFORE tile t's MFMA; ds_write them after the post-compute barrier
// (compiler inserts the vmcnt wait). 3 blocks/CU (launch_bounds (256,3)) gives
// cross-block overlap to hide barriers + HBM latency (m114 mechanism).
template<int EPI, int VSPLIT>   // EPI 0: bf16 out (+VSPLIT Q-scale / vT routing); 1: f32 + resid
__global__ __launch_bounds__(256, 3) void gemm128(
    const bf16* __restrict__ A, const bf16* __restrict__ B,
    const float* __restrict__ bias, const float* __restrict__ resid,
    void* __restrict__ C, bf16* __restrict__ vT, int N, int nbn, int ldc)
{
    __shared__ bf16x8 smA[1024];
    __shared__ bf16x8 smB[1024];
    const int tid  = threadIdx.x;
    const int lane = tid & 63, w = tid >> 6;
    const int wr = w >> 1, wc = w & 1;
    const int l15 = lane & 15, l4 = lane >> 4;
    const int r7 = l15 & 7;

    // XCD-chunked swizzle (gridDim.x % 8 == 0 at both call sites)
    const int nwg = (int)gridDim.x;
    const int bid = (int)blockIdx.x;
    const int sw  = (bid & 7) * (nwg >> 3) + (bid >> 3);
    const int bm0 = (sw / nbn) * 128, bn0 = (sw % nbn) * 128;

    // staging decode: 4 chunks of A + 4 of B per thread
    const int srow = tid >> 3, skb = tid & 7;   // c = q*256+tid -> row = q*32+srow

    uint4 pa[4], pb[4];
    auto PF_LOAD = [&](int t) {
        const int k0 = t * 64;
        #pragma unroll
        for (int q = 0; q < 4; q++) {
            int row = q * 32 + srow;
            pa[q] = *(const uint4*)(A + (size_t)(bm0 + row) * KDIM + k0 + skb * 8);
            pb[q] = *(const uint4*)(B + (size_t)(bn0 + row) * KDIM + k0 + skb * 8);
        }
    };
    auto LDS_WRITE = [&]() {
        #pragma unroll
        for (int q = 0; q < 4; q++) {
            int row = q * 32 + srow;
            smA[row * 8 + (skb ^ (row & 7))] = __builtin_bit_cast(bf16x8, pa[q]);
            smB[row * 8 + (skb ^ (row & 7))] = __builtin_bit_cast(bf16x8, pb[q]);
        }
    };

    f32x4 acc[4][4] = {};

    PF_LOAD(0);
    LDS_WRITE();
    __syncthreads();

    #pragma unroll 1
    for (int t = 0; t < NT_K; ++t) {
        if (t + 1 < NT_K) PF_LOAD(t + 1);    // in flight during compute
        #pragma unroll
        for (int kp = 0; kp < 2; kp++) {
            const int slot = kp * 4 + l4;
            bf16x8 af[4], bfr[4];
            #pragma unroll
            for (int m = 0; m < 4; m++)
                af[m] = smA[(wr * 64 + m * 16 + l15) * 8 + (slot ^ r7)];
            #pragma unroll
            for (int n = 0; n < 4; n++)
                bfr[n] = smB[(wc * 64 + n * 16 + l15) * 8 + (slot ^ r7)];
            #pragma unroll
            for (int m = 0; m < 4; m++)
                #pragma unroll
                for (int n = 0; n < 4; n++)
                    acc[m][n] = __builtin_amdgcn_mfma_f32_16x16x32_bf16(af[m], bfr[n], acc[m][n], 0, 0, 0);
        }
        __syncthreads();                     // everyone done reading this tile
        if (t + 1 < NT_K) {
            LDS_WRITE();                     // vmcnt auto-inserted before pa/pb use
            __syncthreads();
        }
    }

    // epilogue: C/D layout col=lane&15, row=(lane>>4)*4+i
    #pragma unroll
    for (int m = 0; m < 4; m++) {
        #pragma unroll
        for (int n = 0; n < 4; n++) {
            const int col  = bn0 + wc * 64 + n * 16 + l15;
            const int row0 = bm0 + wr * 64 + m * 16 + l4 * 4;
            const float bv = bias[col];
            if (EPI == 1) {
                #pragma unroll
                for (int i = 0; i < 4; i++) {
                    float v = acc[m][n][i] + bv + resid[(size_t)(row0 + i) * N + col];
                    ((float*)C)[(size_t)(row0 + i) * N + col] = v;
                }
            } else if (VSPLIT && bn0 >= 2048) {
                // V -> vT[(g*16+h)*64 + d][512 s], rows i are s-contiguous: one 8B store
                const int cc = col - 2048;
                bf16x4 pk;
                #pragma unroll
                for (int i = 0; i < 4; i++) pk[i] = (bf16)(acc[m][n][i] + bv);
                *(bf16x4*)(vT + ((size_t)((row0 >> 9) * HEADS + (cc >> 6)) * DH + (cc & 63)) * SEGLEN
                               + (row0 & (SEGLEN - 1))) = pk;
            } else {
                const float sc = (VSPLIT && bn0 < 1024) ? 0.125f : 1.0f;  // fold softmax scale into Q
                #pragma unroll
                for (int i = 0; i < 4; i++)
                    ((bf16*)C)[(size_t)(row0 + i) * ldc + col] = (bf16)((acc[m][n][i] + bv) * sc);
            }
        }
    }
}

// ---------------- block-diagonal flash attention ----------------
// grid: (qt=8, h=16, g=32); 256 threads (4 waves), each wave owns 16 q-rows.
__global__ __launch_bounds__(256) void attn_kernel(
    const bf16* __restrict__ qkA, const bf16* __restrict__ vT, bf16* __restrict__ ctx)
{
    const int qt = blockIdx.x, h = blockIdx.y, g = blockIdx.z;
    __shared__ bf16x8 smQP[64 * 8];   // Q tile, then P tile
    __shared__ bf16x8 smK[64 * 8];
    __shared__ bf16x8 smV[64 * 8];    // V^T tile: [d][kv]
    const int tid = threadIdx.x, lane = tid & 63, w = tid >> 6;
    const int l15 = lane & 15, l4 = lane >> 4;
    const int grow0 = g * SEGLEN;
    const size_t vbase = (size_t)(g * HEADS + h) * DH * SEGLEN;

    #pragma unroll
    for (int q = 0; q < 2; q++) {
        int c = tid + 256 * q, r = c >> 3, cb = c & 7;
        uint4 v = *(const uint4*)(qkA + (size_t)(grow0 + qt * 64 + r) * QK_LD + h * 64 + cb * 8);
        smQP[r * 8 + (cb ^ (r & 7))] = __builtin_bit_cast(bf16x8, v);
    }
    __syncthreads();

    bf16x8 qf[2];
    #pragma unroll
    for (int kp = 0; kp < 2; kp++) {
        int row = w * 16 + l15;
        qf[kp] = smQP[row * 8 + ((kp * 4 + l4) ^ (row & 7))];
    }

    f32x4 acc[4] = {};
    float mrow[4], lrow[4];
    #pragma unroll
    for (int i = 0; i < 4; i++) { mrow[i] = -INFINITY; lrow[i] = 0.f; }

    uint4 kr[2][2], vr[2][2];
    auto LOADT = [&](int t, int dst) {
        #pragma unroll
        for (int q = 0; q < 2; q++) {
            int c = tid + 256 * q, r = c >> 3, cb = c & 7;
            kr[dst][q] = *(const uint4*)(qkA + (size_t)(grow0 + t * 64 + r) * QK_LD + 1024 + h * 64 + cb * 8);
            vr[dst][q] = *(const uint4*)(vT + vbase + (size_t)r * SEGLEN + t * 64 + cb * 8);
        }
    };
    LOADT(0, 0);

    #pragma unroll
    for (int t = 0; t < 8; t++) {
        const int cur = t & 1, nxt = cur ^ 1;
        #pragma unroll
        for (int q = 0; q < 2; q++) {
            int c = tid + 256 * q, r = c >> 3, cb = c & 7;
            smK[r * 8 + (cb ^ (r & 7))] = __builtin_bit_cast(bf16x8, kr[cur][q]);
            smV[r * 8 + (cb ^ (r & 7))] = __builtin_bit_cast(bf16x8, vr[cur][q]);
        }
        if (t < 7) LOADT(t + 1, nxt);
        __syncthreads();

        f32x4 s[4] = {};
        #pragma unroll
        for (int kp = 0; kp < 2; kp++) {
            #pragma unroll
            for (int n = 0; n < 4; n++) {
                int row = n * 16 + l15;
                bf16x8 kf = smK[row * 8 + ((kp * 4 + l4) ^ (row & 7))];
                s[n] = __builtin_amdgcn_mfma_f32_16x16x32_bf16(qf[kp], kf, s[n], 0, 0, 0);
            }
        }
        float mx[4];
        #pragma unroll
        for (int i = 0; i < 4; i++) {
            float m0 = fmaxf(fmaxf(s[0][i], s[1][i]), fmaxf(s[2][i], s[3][i]));
            #pragma unroll
            for (int d = 1; d < 16; d <<= 1) m0 = fmaxf(m0, __shfl_xor(m0, d));
            mx[i] = m0;
        }
        int need = 0;
        #pragma unroll
        for (int i = 0; i < 4; i++) need |= (mx[i] > mrow[i] + 8.0f) ? 1 : 0;
        if (__any(need)) {
            #pragma unroll
            for (int i = 0; i < 4; i++) {
                float mn = fmaxf(mrow[i], mx[i]);
                float alpha = __expf(mrow[i] - mn);
                mrow[i] = mn;
                lrow[i] *= alpha;
                #pragma unroll
                for (int n = 0; n < 4; n++) acc[n][i] *= alpha;
            }
        }
        float rsum[4] = {0.f, 0.f, 0.f, 0.f};
        #pragma unroll
        for (int n = 0; n < 4; n++) {
            #pragma unroll
            for (int i = 0; i < 4; i++) {
                float p = __expf(s[n][i] - mrow[i]);
                rsum[i] += p;
                int prow = w * 16 + l4 * 4 + i;
                int pcol = n * 16 + l15;
                ((bf16*)smQP)[prow * 64 + (pcol ^ ((prow & 7) << 3))] = (bf16)p;
            }
        }
        #pragma unroll
        for (int i = 0; i < 4; i++) {
            #pragma unroll
            for (int d = 1; d < 16; d <<= 1) rsum[i] += __shfl_xor(rsum[i], d);
            lrow[i] += rsum[i];
        }
        #pragma unroll
        for (int kp = 0; kp < 2; kp++) {
            int prow = w * 16 + l15;
            bf16x8 pf = smQP[prow * 8 + ((kp * 4 + l4) ^ (prow & 7))];
            #pragma unroll
            for (int n = 0; n < 4; n++) {
                int vrow = n * 16 + l15;
                bf16x8 vf = smV[vrow * 8 + ((kp * 4 + l4) ^ (vrow & 7))];
                acc[n] = __builtin_amdgcn_mfma_f32_16x16x32_bf16(pf, vf, acc[n], 0, 0, 0);
            }
        }
        __syncthreads();
    }

    #pragma unroll
    for (int i = 0; i < 4; i++) {
        float inv = 1.f / lrow[i];
        int row = grow0 + qt * 64 + w * 16 + l4 * 4 + i;
        #pragma unroll
        for (int n = 0; n < 4; n++) {
            int col = h * 64 + n * 16 + l15;
            ctx[(size_t)row * DMODEL + col] = (bf16)(acc[n][i] * inv);
        }
    }
}

// ---------------- residual+GEMM output -> LayerNorm ----------------
__global__ __launch_bounds__(256) void ln_kernel(
    const float* __restrict__ h, const float* __restrict__ gamma,
    const float* __restrict__ beta, float* __restrict__ out)
{
    const int row = blockIdx.x;
    float4 v = ((const float4*)(h + (size_t)row * DMODEL))[threadIdx.x];
    float s  = v.x + v.y + v.z + v.w;
    float ss = v.x * v.x + v.y * v.y + v.z * v.z + v.w * v.w;
    #pragma unroll
    for (int d = 1; d < 64; d <<= 1) { s += __shfl_xor(s, d); ss += __shfl_xor(ss, d); }
    __shared__ float red[8];
    int wv = threadIdx.x >> 6, lane = threadIdx.x & 63;
    if (lane == 0) { red[wv] = s; red[4 + wv] = ss; }
    __syncthreads();
    s  = red[0] + red[1] + red[2] + red[3];
    ss = red[4] + red[5] + red[6] + red[7];
    float mu  = s * (1.f / 1024.f);
    float var = ss * (1.f / 1024.f) - mu * mu;
    float rs  = rsqrtf(var + 1e-5f);
    float4 gv = ((const float4*)gamma)[threadIdx.x];
    float4 bv = ((const float4*)beta)[threadIdx.x];
    float4 o;
    o.x = (v.x - mu) * rs * gv.x + bv.x;
    o.y = (v.y - mu) * rs * gv.y + bv.y;
    o.z = (v.z - mu) * rs * gv.z + bv.z;
    o.w = (v.w - mu) * rs * gv.w + bv.w;
    ((float4*)(out + (size_t)row * DMODEL))[threadIdx.x] = o;
}

// ---------------- launch ----------------
extern "C" void kernel_launch(void* const* d_in, const int* in_sizes, int n_in,
                              void* d_out, int out_size, void* d_ws, size_t ws_size,
                              hipStream_t stream) {
    const float* x     = (const float*)d_in[0];
    // d_in[1] = batch (int64) — fixed 512-row segments, unused
    const float* w_in  = (const float*)d_in[2];
    const float* b_in  = (const float*)d_in[3];
    const float* w_out = (const float*)d_in[4];
    const float* b_out = (const float*)d_in[5];
    const float* gamma = (const float*)d_in[6];
    const float* beta  = (const float*)d_in[7];
    float* out = (float*)d_out;

    // workspace layout (~136 MB):
    //   [0, 32M)     xb  (bf16 x)          -> reused as ctx (bf16) after GEMM1
    //   [32M, 38M)   wb  (bf16 w_in)
    //   [38M, 40M)   wob (bf16 w_out)
    //   [40M, 104M)  qkA (bf16 [N][2048], Q|K; Q pre-scaled) -> reused as h (f32) after attn
    //   [104M, 136M) vT  (bf16 [32*16*64][512], V transposed)
    char* ws = (char*)d_ws;
    bf16*  xb   = (bf16*)ws;
    bf16*  wb   = (bf16*)(ws + 33554432);
    bf16*  wob  = (bf16*)(ws + 39845888);
    bf16*  qkA  = (bf16*)(ws + 41943040);
    bf16*  vT   = (bf16*)(ws + 109051904);
    bf16*  ctxb = xb;
    float* hbuf = (float*)qkA;

    // 1) converts
    cvt_f32_bf16<<<16384, 256, 0, stream>>>(x,     xb,  N_TOK * DMODEL / 4);
    cvt_f32_bf16<<<3072,  256, 0, stream>>>(w_in,  wb,  D3 * DMODEL / 4);
    cvt_f32_bf16<<<1024,  256, 0, stream>>>(w_out, wob, DMODEL * DMODEL / 4);

    // 2) qkv = x @ w_in.T + b_in  -> qkA (Q scaled) + vT (V transposed)
    gemm128<0, 1><<<3072, 256, 0, stream>>>(xb, wb, b_in, nullptr, qkA, vT,
                                            D3, 24, QK_LD);
    // 3) block-diagonal attention -> ctx (bf16)
    attn_kernel<<<dim3(8, 16, 32), 256, 0, stream>>>(qkA, vT, ctxb);

    // 4) h = ctx @ w_out.T + b_out + x  (f32)
    gemm128<1, 0><<<1024, 256, 0, stream>>>(ctxb, wob, b_out, x, hbuf, nullptr,
                                            DMODEL, 8, DMODEL);
    // 5) LayerNorm
    ln_kernel<<<N_TOK, 256, 0, stream>>>(hbuf, gamma, beta, out);
}